// Round 2
// baseline (779.202 us; speedup 1.0000x reference)
//
#include <hip/hip_runtime.h>
#include <stdint.h>

typedef __attribute__((ext_vector_type(8))) short bf16x8;
typedef __attribute__((ext_vector_type(4))) float f32x4;
typedef __attribute__((ext_vector_type(4))) short short4v;

#define DEV __device__ __forceinline__

DEV float bf2f(unsigned short s){ union{unsigned int u; float f;} x; x.u = ((unsigned int)s)<<16; return x.f; }
DEV unsigned short f2bf(float f){ union{float f; unsigned int u;} x; x.f = f; x.u += 0x7fffu + ((x.u>>16)&1u); return (unsigned short)(x.u>>16); }

DEV f32x4 mfma16(bf16x8 a, bf16x8 b, f32x4 c){
  return __builtin_amdgcn_mfma_f32_16x16x32_bf16(a, b, c, 0, 0, 0);
}
DEV f32x4 zero4(){ f32x4 z; z[0]=0.f; z[1]=0.f; z[2]=0.f; z[3]=0.f; return z; }

// ---------------- elementwise f32 -> bf16 ----------------
__global__ __launch_bounds__(256) void k_f32_to_bf16(const float* __restrict__ in, unsigned short* __restrict__ out, int n4){
  int i = blockIdx.x*256 + threadIdx.x;
  if (i < n4){
    float4 v = ((const float4*)in)[i];
    short4v o; o.x=(short)f2bf(v.x); o.y=(short)f2bf(v.y); o.z=(short)f2bf(v.z); o.w=(short)f2bf(v.w);
    ((short4v*)out)[i] = o;
  }
}

// ------------- f32 [R][C] -> bf16 transposed [C][R] -------------
__global__ __launch_bounds__(256) void k_convT(const float* __restrict__ in, unsigned short* __restrict__ out, int R, int Cc){
  __shared__ float t[32][33];
  int c0 = blockIdx.x*32, r0 = blockIdx.y*32;
  int tid = threadIdx.x;
  int row = tid>>3, col4 = (tid&7)*4;
  float4 v = *(const float4*)&in[(size_t)(r0+row)*Cc + c0 + col4];
  t[row][col4+0]=v.x; t[row][col4+1]=v.y; t[row][col4+2]=v.z; t[row][col4+3]=v.w;
  __syncthreads();
  short4v o;
  o.x=(short)f2bf(t[col4+0][row]); o.y=(short)f2bf(t[col4+1][row]);
  o.z=(short)f2bf(t[col4+2][row]); o.w=(short)f2bf(t[col4+3][row]);
  *(short4v*)&out[(size_t)(c0+row)*R + r0 + col4] = o;
}

// ------------- small prep: Wpre*temp, Wpost -> bf16 -------------
__global__ __launch_bounds__(256) void k_prep(const float* __restrict__ wpre, const float* __restrict__ wpost,
                                              const float* __restrict__ temp,
                                              unsigned short* __restrict__ wpre_t, unsigned short* __restrict__ wpost_b){
  int t = threadIdx.x;
  float T = temp[0];
  wpre_t[t]  = f2bf(wpre[t]*T);
  wpost_b[t] = f2bf(wpost[t]);
}

// ------------- GEMM: A[M][K] bf16, Bt[N][K] bf16 -> C[M][N] (bf16 or f32) -------------
template<int OUTF>
__global__ __launch_bounds__(256,2) void k_gemm(const unsigned short* __restrict__ A, const unsigned short* __restrict__ Bt,
                                                void* __restrict__ Cv, int M, int Nn, int K){
  __shared__ unsigned short As[128][72];
  __shared__ unsigned short Bs[128][72];
  int tid = threadIdx.x;
  int n0 = blockIdx.x*128, m0 = blockIdx.y*128;
  int w = tid>>6, lane = tid&63, lg = lane>>4, lp = lane&15;
  int wm = (w>>1)*64, wn = (w&1)*64;
  f32x4 acc[4][4];
  #pragma unroll
  for (int i=0;i<4;++i)
    #pragma unroll
    for (int j=0;j<4;++j) acc[i][j] = zero4();

  for (int kt=0; kt<K; kt+=64){
    #pragma unroll
    for (int cch=0; cch<4; ++cch){
      int e = tid + cch*256; int r = e>>3, cl = (e&7)*8;
      *(bf16x8*)&As[r][cl] = *(const bf16x8*)&A[(size_t)(m0+r)*K + kt + cl];
      *(bf16x8*)&Bs[r][cl] = *(const bf16x8*)&Bt[(size_t)(n0+r)*K + kt + cl];
    }
    __syncthreads();
    #pragma unroll
    for (int ks=0; ks<2; ++ks){
      bf16x8 a[4], b[4];
      #pragma unroll
      for (int mi=0; mi<4; ++mi) a[mi] = *(const bf16x8*)&As[wm+mi*16+lp][ks*32 + lg*8];
      #pragma unroll
      for (int ni=0; ni<4; ++ni) b[ni] = *(const bf16x8*)&Bs[wn+ni*16+lp][ks*32 + lg*8];
      #pragma unroll
      for (int mi=0; mi<4; ++mi)
        #pragma unroll
        for (int ni=0; ni<4; ++ni)
          acc[mi][ni] = mfma16(a[mi], b[ni], acc[mi][ni]);
    }
    __syncthreads();
  }
  #pragma unroll
  for (int mi=0; mi<4; ++mi)
    #pragma unroll
    for (int ni=0; ni<4; ++ni)
      #pragma unroll
      for (int r=0; r<4; ++r){
        int row = m0+wm+mi*16+lg*4+r, col = n0+wn+ni*16+lp;
        if (OUTF) ((float*)Cv)[(size_t)row*Nn+col] = acc[mi][ni][r];
        else ((unsigned short*)Cv)[(size_t)row*Nn+col] = f2bf(acc[mi][ni][r]);
      }
}

// ------------- split qkv, l2norm q/k, write bf16 q/k/v + f32 kv out -------------
__global__ __launch_bounds__(256) void k_split_norm(const unsigned short* __restrict__ qkv,
                                                    unsigned short* __restrict__ q, unsigned short* __restrict__ k,
                                                    unsigned short* __restrict__ v, float* __restrict__ kv_out){
  int w = threadIdx.x>>6, lane = threadIdx.x&63;
  int widx = blockIdx.x*4 + w;            // (b*2048+n)*16 + h
  int h = widx & 15; int bn = widx >> 4;
  int b = bn >> 11; int n = bn & 2047;
  size_t base = (size_t)bn*3072 + h*192 + lane*3;
  float qv = bf2f(qkv[base]), kvv = bf2f(qkv[base+1]), vv = bf2f(qkv[base+2]);
  float nq = qv*qv, nk = kvv*kvv;
  #pragma unroll
  for (int m=1; m<64; m<<=1){ nq += __shfl_xor(nq, m); nk += __shfl_xor(nk, m); }
  float qn = qv / fmaxf(sqrtf(nq), 1e-12f);
  float kn = kvv / fmaxf(sqrtf(nk), 1e-12f);
  size_t idx = ((size_t)(b*16+h)*2048 + n)*64 + lane;
  q[idx] = f2bf(qn); k[idx] = f2bf(kn); v[idx] = f2bf(vv);
  kv_out[idx] = kn;
  kv_out[4194304 + idx] = vv;
}

// ------------- v [bh][n][64] -> vt [bh][64][n] (bf16) -------------
__global__ __launch_bounds__(256) void k_transpose_v(const unsigned short* __restrict__ v, unsigned short* __restrict__ vt){
  __shared__ unsigned short t[64][72];
  int bh = blockIdx.y; int n0 = blockIdx.x*64;
  int tid = threadIdx.x;
  #pragma unroll
  for (int cch=0; cch<2; ++cch){
    int e = tid + cch*256; int r = e>>3, c8 = (e&7)*8;
    *(bf16x8*)&t[r][c8] = *(const bf16x8*)&v[((size_t)bh*2048 + n0 + r)*64 + c8];
  }
  __syncthreads();
  #pragma unroll
  for (int cch=0; cch<2; ++cch){
    int e = tid + cch*256; int d = e>>3, nn8 = (e&7)*8;
    bf16x8 o;
    #pragma unroll
    for (int i=0;i<8;++i) o[i] = (short)t[nn8+i][d];
    *(bf16x8*)&vt[((size_t)bh*64 + d)*2048 + n0 + nn8] = o;
  }
}

// ------------- vsum[bg][d] = sum_n v[bg][n][d] -------------
__global__ __launch_bounds__(256) void k_vsum(const unsigned short* __restrict__ v, float* __restrict__ vsum){
  int bg = blockIdx.x;
  int d = threadIdx.x & 63, part = threadIdx.x>>6;
  float s = 0.f;
  for (int n = part*512; n < part*512+512; ++n) s += bf2f(v[((size_t)bg*2048 + n)*64 + d]);
  __shared__ float red[4][64];
  red[part][d] = s; __syncthreads();
  if (part==0) vsum[bg*64 + d] = red[0][d]+red[1][d]+red[2][d]+red[3][d];
}

// ------------- fused talking-heads attention (two-pass flash) -------------
// block = (i-tile of 16 rows, batch); 8 waves; Jtile=32.
// LDS: S/P buffer [512 ij][80B] = 40960 ; Atilde [256 rows][80B] = 20480 ; total 61440.
__global__ __launch_bounds__(512,2) void k_attn(
    const unsigned short* __restrict__ q,
    const unsigned short* __restrict__ kk,
    const unsigned short* __restrict__ vt,
    const float* __restrict__ pos_bias,
    const unsigned char* __restrict__ mask,
    const unsigned short* __restrict__ wpre_t,
    const unsigned short* __restrict__ wpost_b,
    const float* __restrict__ bpre,
    const float* __restrict__ bpost,
    const float* __restrict__ vsum,
    unsigned short* __restrict__ attn_out)
{
  extern __shared__ char smem[];
  unsigned short* Al = (unsigned short*)(smem + 40960);   // stride 40 shorts (80B)
  const int tid = threadIdx.x;
  const int w = tid>>6, lane = tid&63, lg = lane>>4, lp = lane&15;
  const int bid = blockIdx.x, it = bid>>1, b = bid&1;
  const int i0 = it*16;

  // zero h-pad region (h slots 16..31) of S buffer, once
  for (int ij = tid; ij < 512; ij += 512){
    *(f32x4*)(smem + ij*80 + 32) = zero4();
    *(f32x4*)(smem + ij*80 + 48) = zero4();
  }

  // Q fragments (2 heads per wave, k-dim = D=64 -> 2 frags)
  bf16x8 qf[2][2];
  #pragma unroll
  for (int hh=0; hh<2; ++hh){
    int h = 2*w+hh;
    const unsigned short* qb = q + ((size_t)(b*16+h)*2048 + i0 + lp)*64;
    qf[hh][0] = *(const bf16x8*)(qb + lg*8);
    qf[hh][1] = *(const bf16x8*)(qb + 32 + lg*8);
  }
  // head-mix A fragments (K padded 16->32: lanes lg>=2 hold zeros)
  bf16x8 preA, postA;
  #pragma unroll
  for (int i=0;i<8;++i){ preA[i]=0; postA[i]=0; }
  if (lg < 2){
    preA  = *(const bf16x8*)&wpre_t[lp*16 + lg*8];
    postA = *(const bf16x8*)&wpost_b[lp*16 + lg*8];
  }
  float bpre_r[4];
  #pragma unroll
  for (int r=0;r<4;++r) bpre_r[r] = bpre[lg*4+r];

  float mrun[2][4], lrun[2][4];
  #pragma unroll
  for (int hh=0; hh<2; ++hh)
    #pragma unroll
    for (int r=0;r<4;++r){ mrun[hh][r] = -3.0e38f; lrun[hh][r] = 0.f; }

  const size_t kbase0 = (size_t)(b*16 + 2*w)*2048*64;
  const size_t kbase1 = (size_t)(b*16 + 2*w+1)*2048*64;

  __syncthreads();

  // ================= PASS 1: running max/sum =================
  for (int j0=0; j0<2048; j0+=32){
    f32x4 s0[2], s1[2];
    #pragma unroll
    for (int jf=0;jf<2;++jf){ s0[jf]=zero4(); s1[jf]=zero4(); }
    #pragma unroll
    for (int kf=0; kf<2; ++kf){
      #pragma unroll
      for (int jf=0; jf<2; ++jf){
        size_t off = (size_t)(j0 + jf*16 + lp)*64 + kf*32 + lg*8;
        bf16x8 k0 = *(const bf16x8*)(kk + kbase0 + off);
        bf16x8 k1 = *(const bf16x8*)(kk + kbase1 + off);
        s0[jf] = mfma16(qf[0][kf], k0, s0[jf]);
        s1[jf] = mfma16(qf[1][kf], k1, s1[jf]);
      }
    }
    #pragma unroll
    for (int jf=0;jf<2;++jf)
      #pragma unroll
      for (int r=0;r<4;++r){
        int ij = (lg*4+r)*32 + jf*16 + lp;
        unsigned int pk = (unsigned int)f2bf(s0[jf][r]) | ((unsigned int)f2bf(s1[jf][r])<<16);
        *(unsigned int*)(smem + ij*80 + w*4) = pk;
      }
    __syncthreads();
    float va[4][4];
    #pragma unroll
    for (int cc=0; cc<4; ++cc){
      int c = w*4+cc;
      bf16x8 bfr = *(const bf16x8*)(smem + (c*16+lp)*80 + lg*16);
      f32x4 pa = mfma16(preA, bfr, zero4());
      int ii = 2*w + (cc>>1);
      int jglob = j0 + (cc&1)*16 + lp;
      float mk = mask[b*2048 + jglob] ? -1e30f : 0.f;
      #pragma unroll
      for (int r=0;r<4;++r){
        float pb = pos_bias[((size_t)(lg*4+r)*2048 + (i0+ii))*2048 + jglob];
        va[cc][r] = pa[r] + bpre_r[r] + pb + mk;
      }
    }
    #pragma unroll
    for (int hh=0; hh<2; ++hh){
      #pragma unroll
      for (int r=0;r<4;++r){
        float tm = fmaxf(va[2*hh][r], va[2*hh+1][r]);
        #pragma unroll
        for (int mm=1; mm<16; mm<<=1) tm = fmaxf(tm, __shfl_xor(tm, mm));
        float nm = fmaxf(mrun[hh][r], tm);
        float se = __expf(va[2*hh][r]-nm) + __expf(va[2*hh+1][r]-nm);
        #pragma unroll
        for (int mm=1; mm<16; mm<<=1) se += __shfl_xor(se, mm);
        lrun[hh][r] = lrun[hh][r]*__expf(mrun[hh][r]-nm) + se;
        mrun[hh][r] = nm;
      }
    }
    __syncthreads();
  }

  float linv[2][4];
  #pragma unroll
  for (int hh=0; hh<2; ++hh)
    #pragma unroll
    for (int r=0;r<4;++r) linv[hh][r] = 1.f / lrun[hh][r];

  // ================= PASS 2: normalize, post-mix, PV =================
  f32x4 oacc[2][4];
  #pragma unroll
  for (int hh=0; hh<2; ++hh)
    #pragma unroll
    for (int df=0; df<4; ++df) oacc[hh][df] = zero4();

  for (int j0=0; j0<2048; j0+=32){
    f32x4 s0[2], s1[2];
    #pragma unroll
    for (int jf=0;jf<2;++jf){ s0[jf]=zero4(); s1[jf]=zero4(); }
    #pragma unroll
    for (int kf=0; kf<2; ++kf){
      #pragma unroll
      for (int jf=0; jf<2; ++jf){
        size_t off = (size_t)(j0 + jf*16 + lp)*64 + kf*32 + lg*8;
        bf16x8 k0 = *(const bf16x8*)(kk + kbase0 + off);
        bf16x8 k1 = *(const bf16x8*)(kk + kbase1 + off);
        s0[jf] = mfma16(qf[0][kf], k0, s0[jf]);
        s1[jf] = mfma16(qf[1][kf], k1, s1[jf]);
      }
    }
    #pragma unroll
    for (int jf=0;jf<2;++jf)
      #pragma unroll
      for (int r=0;r<4;++r){
        int ij = (lg*4+r)*32 + jf*16 + lp;
        unsigned int pk = (unsigned int)f2bf(s0[jf][r]) | ((unsigned int)f2bf(s1[jf][r])<<16);
        *(unsigned int*)(smem + ij*80 + w*4) = pk;
      }
    __syncthreads();
    float va[4][4];
    #pragma unroll
    for (int cc=0; cc<4; ++cc){
      int c = w*4+cc;
      bf16x8 bfr = *(const bf16x8*)(smem + (c*16+lp)*80 + lg*16);
      f32x4 pa = mfma16(preA, bfr, zero4());
      int ii = 2*w + (cc>>1);
      int jglob = j0 + (cc&1)*16 + lp;
      float mk = mask[b*2048 + jglob] ? -1e30f : 0.f;
      #pragma unroll
      for (int r=0;r<4;++r){
        float pb = pos_bias[((size_t)(lg*4+r)*2048 + (i0+ii))*2048 + jglob];
        va[cc][r] = pa[r] + bpre_r[r] + pb + mk;
      }
    }
    __syncthreads();
    // normalized P -> same LDS buffer, [ij][g]
    #pragma unroll
    for (int cc=0; cc<4; ++cc){
      int hh = cc>>1;
      int ij = (w*4+cc)*16 + lp;
      short4v p4;
      p4.x = (short)f2bf(__expf(va[cc][0]-mrun[hh][0])*linv[hh][0]);
      p4.y = (short)f2bf(__expf(va[cc][1]-mrun[hh][1])*linv[hh][1]);
      p4.z = (short)f2bf(__expf(va[cc][2]-mrun[hh][2])*linv[hh][2]);
      p4.w = (short)f2bf(__expf(va[cc][3]-mrun[hh][3])*linv[hh][3]);
      *(short4v*)(smem + ij*80 + lg*8) = p4;
    }
    __syncthreads();
    // post-mix -> Atilde LDS
    #pragma unroll
    for (int cc=0; cc<4; ++cc){
      int c = w*4+cc;
      bf16x8 bfr = *(const bf16x8*)(smem + (c*16+lp)*80 + lg*16);
      f32x4 aa = mfma16(postA, bfr, zero4());
      int ii = 2*w + (cc>>1);
      int jj = (cc&1)*16 + lp;
      #pragma unroll
      for (int r=0;r<4;++r) Al[((lg*4+r)*16 + ii)*40 + jj] = f2bf(aa[r]);
    }
    __syncthreads();
    // PV
    #pragma unroll
    for (int hh=0; hh<2; ++hh){
      int gg = 2*w+hh;
      bf16x8 af = *(const bf16x8*)(smem + 40960 + (size_t)(gg*16+lp)*80 + lg*16);
      #pragma unroll
      for (int df=0; df<4; ++df){
        bf16x8 vf = *(const bf16x8*)(vt + ((size_t)(b*16+gg)*64 + df*16 + lp)*2048 + j0 + lg*8);
        oacc[hh][df] = mfma16(af, vf, oacc[hh][df]);
      }
    }
    __syncthreads();
  }

  // epilogue: + bpost[g]*Vsum, store bf16 [b,n][g*64+d]
  #pragma unroll
  for (int hh=0; hh<2; ++hh){
    int gg = 2*w+hh;
    float bp = bpost[gg];
    #pragma unroll
    for (int df=0; df<4; ++df){
      int d = df*16+lp;
      float vs = vsum[(b*16+gg)*64 + d];
      #pragma unroll
      for (int r=0;r<4;++r){
        float o = oacc[hh][df][r] + bp*vs;
        attn_out[((size_t)(b*2048 + i0 + lg*4 + r))*1024 + gg*64 + d] = f2bf(o);
      }
    }
  }
}

// ======================================================================
extern "C" void kernel_launch(void* const* d_in, const int* in_sizes, int n_in,
                              void* d_out, int out_size, void* d_ws, size_t ws_size,
                              hipStream_t stream)
{
  const float* x        = (const float*)d_in[0];
  const float* pos_bias = (const float*)d_in[1];
  const unsigned char* mask = (const unsigned char*)d_in[2];
  const float* Wqkv     = (const float*)d_in[3];
  const float* Wout     = (const float*)d_in[4];
  const float* Wpre     = (const float*)d_in[5];
  const float* bpre     = (const float*)d_in[6];
  const float* Wpost    = (const float*)d_in[7];
  const float* bpost    = (const float*)d_in[8];
  const float* temp     = (const float*)d_in[9];
  float* out = (float*)d_out;
  float* kv_out = out + 4194304;

  char* ws = (char*)d_ws;
  unsigned short* XB    = (unsigned short*)(ws + 0);          // x bf16 (8.39MB); reused as attn_out later
  unsigned short* WT    = (unsigned short*)(ws + 8388608);    // Wqkv^T bf16 (6.29MB); reused as Wout^T later
  unsigned short* QKV   = (unsigned short*)(ws + 14680064);   // qkv bf16 (25.2MB); reused as VT + small later
  unsigned short* WPRE  = (unsigned short*)(ws + 23068672);
  unsigned short* WPOST = (unsigned short*)(ws + 23069184);
  float*          VSUM  = (float*)        (ws + 23069696);
  unsigned short* Q     = (unsigned short*)(ws + 39845888);
  unsigned short* KB    = (unsigned short*)(ws + 48234496);
  unsigned short* VB    = (unsigned short*)(ws + 56623104);
  unsigned short* VT    = QKV;
  unsigned short* AO    = XB;
  unsigned short* WOT   = WT;

  // 1. convert x -> bf16
  k_f32_to_bf16<<<4096, 256, 0, stream>>>(x, XB, 1048576);
  // 2. Wqkv [1024][3072] -> WT [3072][1024] bf16
  k_convT<<<dim3(96,32), 256, 0, stream>>>(Wqkv, WT, 1024, 3072);
  // 3. qkv = x @ Wqkv  (bf16 out)
  k_gemm<0><<<dim3(24,32), 256, 0, stream>>>(XB, WT, (void*)QKV, 4096, 3072, 1024);
  // 4. split + l2norm + kv f32 output
  k_split_norm<<<16384, 256, 0, stream>>>(QKV, Q, KB, VB, kv_out);
  // 5. v -> vt (transposed bf16)
  k_transpose_v<<<dim3(32,32), 256, 0, stream>>>(VB, VT);
  // 6. vsum
  k_vsum<<<32, 256, 0, stream>>>(VB, VSUM);
  // 7. small weights prep
  k_prep<<<1, 256, 0, stream>>>(Wpre, Wpost, temp, WPRE, WPOST);
  // 8. Wout [1024][1024] -> WOT [1024][1024] transposed bf16
  k_convT<<<dim3(32,32), 256, 0, stream>>>(Wout, WOT, 1024, 1024);
  // 9. fused attention
  k_attn<<<256, 512, 61440, stream>>>(Q, KB, VT, pos_bias, mask, WPRE, WPOST, bpre, bpost, VSUM, AO);
  // 10. out = attn_out @ Wout (f32 out)
  k_gemm<1><<<dim3(8,32), 256, 0, stream>>>(AO, WOT, d_out, 4096, 1024, 1024);
}

// Round 3
// 703.692 us; speedup vs baseline: 1.1073x; 1.1073x over previous
//
#include <hip/hip_runtime.h>
#include <stdint.h>

typedef __attribute__((ext_vector_type(8))) short bf16x8;
typedef __attribute__((ext_vector_type(4))) float f32x4;
typedef __attribute__((ext_vector_type(4))) short short4v;

#define DEV __device__ __forceinline__

DEV float bf2f(unsigned short s){ union{unsigned int u; float f;} x; x.u = ((unsigned int)s)<<16; return x.f; }
DEV unsigned short f2bf(float f){ union{float f; unsigned int u;} x; x.f = f; x.u += 0x7fffu + ((x.u>>16)&1u); return (unsigned short)(x.u>>16); }

DEV f32x4 mfma16(bf16x8 a, bf16x8 b, f32x4 c){
  return __builtin_amdgcn_mfma_f32_16x16x32_bf16(a, b, c, 0, 0, 0);
}
DEV f32x4 zero4(){ f32x4 z; z[0]=0.f; z[1]=0.f; z[2]=0.f; z[3]=0.f; return z; }
DEV bf16x8 zerob(){ bf16x8 z; z[0]=0;z[1]=0;z[2]=0;z[3]=0;z[4]=0;z[5]=0;z[6]=0;z[7]=0; return z; }

// ---------------- elementwise f32 -> bf16 ----------------
__global__ __launch_bounds__(256) void k_f32_to_bf16(const float* __restrict__ in, unsigned short* __restrict__ out, int n4){
  int i = blockIdx.x*256 + threadIdx.x;
  if (i < n4){
    float4 v = ((const float4*)in)[i];
    short4v o; o.x=(short)f2bf(v.x); o.y=(short)f2bf(v.y); o.z=(short)f2bf(v.z); o.w=(short)f2bf(v.w);
    ((short4v*)out)[i] = o;
  }
}

// ------------- f32 [R][C] -> bf16 transposed [C][R] -------------
__global__ __launch_bounds__(256) void k_convT(const float* __restrict__ in, unsigned short* __restrict__ out, int R, int Cc){
  __shared__ float t[32][33];
  int c0 = blockIdx.x*32, r0 = blockIdx.y*32;
  int tid = threadIdx.x;
  int row = tid>>3, col4 = (tid&7)*4;
  float4 v = *(const float4*)&in[(size_t)(r0+row)*Cc + c0 + col4];
  t[row][col4+0]=v.x; t[row][col4+1]=v.y; t[row][col4+2]=v.z; t[row][col4+3]=v.w;
  __syncthreads();
  short4v o;
  o.x=(short)f2bf(t[col4+0][row]); o.y=(short)f2bf(t[col4+1][row]);
  o.z=(short)f2bf(t[col4+2][row]); o.w=(short)f2bf(t[col4+3][row]);
  *(short4v*)&out[(size_t)(c0+row)*R + r0 + col4] = o;
}

// ------------- small prep: Wpre*temp, Wpost -> bf16 ([g][h] row-major) -------------
__global__ __launch_bounds__(256) void k_prep(const float* __restrict__ wpre, const float* __restrict__ wpost,
                                              const float* __restrict__ temp,
                                              unsigned short* __restrict__ wpre_t, unsigned short* __restrict__ wpost_b){
  int t = threadIdx.x;
  float T = temp[0];
  wpre_t[t]  = f2bf(wpre[t]*T);
  wpost_b[t] = f2bf(wpost[t]);
}

// ------------- GEMM: A[M][K] bf16, Bt[N][K] bf16 -> C[M][N] (bf16 or f32) -------------
template<int OUTF>
__global__ __launch_bounds__(256,2) void k_gemm(const unsigned short* __restrict__ A, const unsigned short* __restrict__ Bt,
                                                void* __restrict__ Cv, int M, int Nn, int K){
  __shared__ unsigned short As[128][72];
  __shared__ unsigned short Bs[128][72];
  int tid = threadIdx.x;
  int n0 = blockIdx.x*128, m0 = blockIdx.y*128;
  int w = tid>>6, lane = tid&63, lg = lane>>4, lp = lane&15;
  int wm = (w>>1)*64, wn = (w&1)*64;
  f32x4 acc[4][4];
  #pragma unroll
  for (int i=0;i<4;++i)
    #pragma unroll
    for (int j=0;j<4;++j) acc[i][j] = zero4();

  for (int kt=0; kt<K; kt+=64){
    #pragma unroll
    for (int cch=0; cch<4; ++cch){
      int e = tid + cch*256; int r = e>>3, cl = (e&7)*8;
      *(bf16x8*)&As[r][cl] = *(const bf16x8*)&A[(size_t)(m0+r)*K + kt + cl];
      *(bf16x8*)&Bs[r][cl] = *(const bf16x8*)&Bt[(size_t)(n0+r)*K + kt + cl];
    }
    __syncthreads();
    #pragma unroll
    for (int ks=0; ks<2; ++ks){
      bf16x8 a[4], b[4];
      #pragma unroll
      for (int mi=0; mi<4; ++mi) a[mi] = *(const bf16x8*)&As[wm+mi*16+lp][ks*32 + lg*8];
      #pragma unroll
      for (int ni=0; ni<4; ++ni) b[ni] = *(const bf16x8*)&Bs[wn+ni*16+lp][ks*32 + lg*8];
      #pragma unroll
      for (int mi=0; mi<4; ++mi)
        #pragma unroll
        for (int ni=0; ni<4; ++ni)
          acc[mi][ni] = mfma16(a[mi], b[ni], acc[mi][ni]);
    }
    __syncthreads();
  }
  #pragma unroll
  for (int mi=0; mi<4; ++mi)
    #pragma unroll
    for (int ni=0; ni<4; ++ni)
      #pragma unroll
      for (int r=0; r<4; ++r){
        int row = m0+wm+mi*16+lg*4+r, col = n0+wn+ni*16+lp;
        if (OUTF) ((float*)Cv)[(size_t)row*Nn+col] = acc[mi][ni][r];
        else ((unsigned short*)Cv)[(size_t)row*Nn+col] = f2bf(acc[mi][ni][r]);
      }
}

// ------------- split qkv, l2norm q/k, write bf16 q/k/v + f32 kv out -------------
__global__ __launch_bounds__(256) void k_split_norm(const unsigned short* __restrict__ qkv,
                                                    unsigned short* __restrict__ q, unsigned short* __restrict__ k,
                                                    unsigned short* __restrict__ v, float* __restrict__ kv_out){
  int w = threadIdx.x>>6, lane = threadIdx.x&63;
  int widx = blockIdx.x*4 + w;            // (b*2048+n)*16 + h
  int h = widx & 15; int bn = widx >> 4;
  int b = bn >> 11; int n = bn & 2047;
  size_t base = (size_t)bn*3072 + h*192 + lane*3;
  float qv = bf2f(qkv[base]), kvv = bf2f(qkv[base+1]), vv = bf2f(qkv[base+2]);
  float nq = qv*qv, nk = kvv*kvv;
  #pragma unroll
  for (int m=1; m<64; m<<=1){ nq += __shfl_xor(nq, m); nk += __shfl_xor(nk, m); }
  float qn = qv / fmaxf(sqrtf(nq), 1e-12f);
  float kn = kvv / fmaxf(sqrtf(nk), 1e-12f);
  size_t idx = ((size_t)(b*16+h)*2048 + n)*64 + lane;
  q[idx] = f2bf(qn); k[idx] = f2bf(kn); v[idx] = f2bf(vv);
  kv_out[idx] = kn;
  kv_out[4194304 + idx] = vv;
}

// ------------- v [bh][n][64] -> vt [bh][64][n] (bf16) -------------
__global__ __launch_bounds__(256) void k_transpose_v(const unsigned short* __restrict__ v, unsigned short* __restrict__ vt){
  __shared__ unsigned short t[64][72];
  int bh = blockIdx.y; int n0 = blockIdx.x*64;
  int tid = threadIdx.x;
  #pragma unroll
  for (int cch=0; cch<2; ++cch){
    int e = tid + cch*256; int r = e>>3, c8 = (e&7)*8;
    *(bf16x8*)&t[r][c8] = *(const bf16x8*)&v[((size_t)bh*2048 + n0 + r)*64 + c8];
  }
  __syncthreads();
  #pragma unroll
  for (int cch=0; cch<2; ++cch){
    int e = tid + cch*256; int d = e>>3, nn8 = (e&7)*8;
    bf16x8 o;
    #pragma unroll
    for (int i=0;i<8;++i) o[i] = (short)t[nn8+i][d];
    *(bf16x8*)&vt[((size_t)bh*64 + d)*2048 + n0 + nn8] = o;
  }
}

// ------------- vsum[bg][d] = sum_n v[bg][n][d] -------------
__global__ __launch_bounds__(256) void k_vsum(const unsigned short* __restrict__ v, float* __restrict__ vsum){
  int bg = blockIdx.x;
  int d = threadIdx.x & 63, part = threadIdx.x>>6;
  float s = 0.f;
  for (int n = part*512; n < part*512+512; ++n) s += bf2f(v[((size_t)bg*2048 + n)*64 + d]);
  __shared__ float red[4][64];
  red[part][d] = s; __syncthreads();
  if (part==0) vsum[bg*64 + d] = red[0][d]+red[1][d]+red[2][d]+red[3][d];
}

// =================== PASS 1: per-row max & exp-sum (j-split 4) ===================
// grid 1024: bid = it*8 + b*4 + js ; 512 thr; LDS 40KB (3 blocks/CU)
__global__ __launch_bounds__(512,6) void k_pass1(
    const unsigned short* __restrict__ q,
    const unsigned short* __restrict__ kk,
    const float* __restrict__ pos_bias,
    const unsigned char* __restrict__ mask,
    const unsigned short* __restrict__ wpre_t,
    const float* __restrict__ bpre,
    float* __restrict__ part_m,
    float* __restrict__ part_l)
{
  __shared__ __align__(16) char smem[40960];
  const int tid = threadIdx.x;
  const int w = tid>>6, lane = tid&63, lg = lane>>4, lp = lane&15;
  const int bid = blockIdx.x;
  const int js = bid & 3, b = (bid>>2)&1, it = bid>>3;
  const int i0 = it*16, jsb = js*512;

  // zero k-pad bytes 32..63 of all 512 rows (persists: writes only touch 0..31)
  *(f32x4*)(smem + tid*80 + 32) = zero4();
  *(f32x4*)(smem + tid*80 + 48) = zero4();

  bf16x8 qf[2][2];
  #pragma unroll
  for (int hh=0; hh<2; ++hh){
    const unsigned short* qb = q + ((size_t)(b*16+2*w+hh)*2048 + i0 + lp)*64;
    qf[hh][0] = *(const bf16x8*)(qb + lg*8);
    qf[hh][1] = *(const bf16x8*)(qb + 32 + lg*8);
  }
  bf16x8 preB = zerob();
  if (lg < 2) preB = *(const bf16x8*)&wpre_t[lp*16 + lg*8];
  const float bpre_g = bpre[lp];

  float m[2], s[2];
  m[0] = -3.0e38f; m[1] = -3.0e38f; s[0] = 0.f; s[1] = 0.f;
  const size_t kbase0 = (size_t)(b*16 + 2*w)*131072;
  const size_t kbase1 = (size_t)(b*16 + 2*w+1)*131072;

  __syncthreads();

  for (int t=0; t<16; ++t){
    const int j0 = jsb + t*32;
    f32x4 s0[2], s1[2];
    #pragma unroll
    for (int jf=0;jf<2;++jf){ s0[jf]=zero4(); s1[jf]=zero4(); }
    #pragma unroll
    for (int kf=0; kf<2; ++kf){
      #pragma unroll
      for (int jf=0; jf<2; ++jf){
        size_t off = (size_t)(j0 + jf*16 + lp)*64 + kf*32 + lg*8;
        bf16x8 k0 = *(const bf16x8*)(kk + kbase0 + off);
        bf16x8 k1 = *(const bf16x8*)(kk + kbase1 + off);
        s0[jf] = mfma16(qf[0][kf], k0, s0[jf]);
        s1[jf] = mfma16(qf[1][kf], k1, s1[jf]);
      }
    }
    #pragma unroll
    for (int jf=0;jf<2;++jf)
      #pragma unroll
      for (int r=0;r<4;++r){
        int ij = (lg*4+r)*32 + jf*16 + lp;
        unsigned int pk = (unsigned int)f2bf(s0[jf][r]) | ((unsigned int)f2bf(s1[jf][r])<<16);
        *(unsigned int*)(smem + ij*80 + w*4) = pk;
      }
    __syncthreads();

    unsigned int mku0 = *(const unsigned int*)(mask + b*2048 + j0 + lg*4);
    unsigned int mku1 = *(const unsigned int*)(mask + b*2048 + j0 + 16 + lg*4);
    #pragma unroll
    for (int cc=0; cc<4; ++cc){
      int c = w*4+cc;
      bf16x8 afr = *(const bf16x8*)(smem + (c*16+lp)*80 + lg*16);
      f32x4 pa = mfma16(afr, preB, zero4());
      int il = 2*w + (cc>>1);
      int jl = (cc&1)*16 + lg*4;
      float4 pb = *(const float4*)&pos_bias[((size_t)lp*2048 + (i0+il))*2048 + j0 + jl];
      unsigned int mku = (cc&1) ? mku1 : mku0;
      float va0 = pa[0] + pb.x + bpre_g + (((mku    )&255u) ? -1e30f : 0.f);
      float va1 = pa[1] + pb.y + bpre_g + (((mku>> 8)&255u) ? -1e30f : 0.f);
      float va2 = pa[2] + pb.z + bpre_g + (((mku>>16)&255u) ? -1e30f : 0.f);
      float va3 = pa[3] + pb.w + bpre_g + (((mku>>24)&255u) ? -1e30f : 0.f);
      int ii = cc>>1;
      float vm = fmaxf(fmaxf(va0,va1), fmaxf(va2,va3));
      float nm = fmaxf(m[ii], vm);
      s[ii] = s[ii]*__expf(m[ii]-nm) + __expf(va0-nm)+__expf(va1-nm)+__expf(va2-nm)+__expf(va3-nm);
      m[ii] = nm;
    }
    __syncthreads();
  }

  // butterfly over lg (lanes sharing same g=lp, i)
  #pragma unroll
  for (int ii=0; ii<2; ++ii){
    #pragma unroll
    for (int mk_=16; mk_<=32; mk_<<=1){
      float m2 = __shfl_xor(m[ii], mk_);
      float l2 = __shfl_xor(s[ii], mk_);
      float nm = fmaxf(m[ii], m2);
      s[ii] = s[ii]*__expf(m[ii]-nm) + l2*__expf(m2-nm);
      m[ii] = nm;
    }
  }
  if (lg == 0){
    int pidx = ((b*128+it)*4 + js)*256;
    #pragma unroll
    for (int ii=0; ii<2; ++ii){
      part_m[pidx + (2*w+ii)*16 + lp] = m[ii];
      part_l[pidx + (2*w+ii)*16 + lp] = s[ii];
    }
  }
}

// =================== PASS 2: recompute, normalize, post-mix, PV (j-split 2) ===================
// grid 512: bid = it*4 + b*2 + js ; 512 thr; LDS 60KB (2 blocks/CU)
__global__ __launch_bounds__(512,4) void k_pass2(
    const unsigned short* __restrict__ q,
    const unsigned short* __restrict__ kk,
    const unsigned short* __restrict__ vt,
    const float* __restrict__ pos_bias,
    const unsigned char* __restrict__ mask,
    const unsigned short* __restrict__ wpre_t,
    const unsigned short* __restrict__ wpost_b,
    const float* __restrict__ bpre,
    const float* __restrict__ bpost,
    const float* __restrict__ vsum,
    const float* __restrict__ part_m,
    const float* __restrict__ part_l,
    float* __restrict__ pout0,
    float* __restrict__ pout1)
{
  __shared__ __align__(16) char smem[61440];   // S/P: [512][80] ; Al: [256][80] @40960
  const int tid = threadIdx.x;
  const int w = tid>>6, lane = tid&63, lg = lane>>4, lp = lane&15;
  const int bid = blockIdx.x;
  const int js = bid & 1, b = (bid>>1)&1, it = bid>>2;
  const int i0 = it*16, jsb = js*1024;

  *(f32x4*)(smem + tid*80 + 32) = zero4();
  *(f32x4*)(smem + tid*80 + 48) = zero4();

  bf16x8 qf[2][2];
  #pragma unroll
  for (int hh=0; hh<2; ++hh){
    const unsigned short* qb = q + ((size_t)(b*16+2*w+hh)*2048 + i0 + lp)*64;
    qf[hh][0] = *(const bf16x8*)(qb + lg*8);
    qf[hh][1] = *(const bf16x8*)(qb + 32 + lg*8);
  }
  bf16x8 preB = zerob(), postB = zerob();
  if (lg < 2){
    preB  = *(const bf16x8*)&wpre_t[lp*16 + lg*8];
    postB = *(const bf16x8*)&wpost_b[lp*16 + lg*8];
  }
  const float bpre_g = bpre[lp];

  // combine split partials -> final (m, 1/l) per (g=lp, i=2w+ii)
  float mC[2], linvC[2];
  {
    float lC[2]; mC[0]=mC[1]=-3.0e38f; lC[0]=lC[1]=0.f;
    int base = ((b*128+it)*4)*256;
    #pragma unroll
    for (int sj=0; sj<4; ++sj){
      #pragma unroll
      for (int ii=0; ii<2; ++ii){
        float mp  = part_m[base + sj*256 + (2*w+ii)*16 + lp];
        float lpv = part_l[base + sj*256 + (2*w+ii)*16 + lp];
        float nm = fmaxf(mC[ii], mp);
        lC[ii] = lC[ii]*__expf(mC[ii]-nm) + lpv*__expf(mp-nm);
        mC[ii] = nm;
      }
    }
    linvC[0] = 1.f/lC[0]; linvC[1] = 1.f/lC[1];
  }

  f32x4 oacc[2][4];
  #pragma unroll
  for (int hh=0; hh<2; ++hh)
    #pragma unroll
    for (int df=0; df<4; ++df) oacc[hh][df] = zero4();

  const size_t kbase0 = (size_t)(b*16 + 2*w)*131072;
  const size_t kbase1 = (size_t)(b*16 + 2*w+1)*131072;

  __syncthreads();

  for (int t=0; t<32; ++t){
    const int j0 = jsb + t*32;
    f32x4 s0[2], s1[2];
    #pragma unroll
    for (int jf=0;jf<2;++jf){ s0[jf]=zero4(); s1[jf]=zero4(); }
    #pragma unroll
    for (int kf=0; kf<2; ++kf){
      #pragma unroll
      for (int jf=0; jf<2; ++jf){
        size_t off = (size_t)(j0 + jf*16 + lp)*64 + kf*32 + lg*8;
        bf16x8 k0 = *(const bf16x8*)(kk + kbase0 + off);
        bf16x8 k1 = *(const bf16x8*)(kk + kbase1 + off);
        s0[jf] = mfma16(qf[0][kf], k0, s0[jf]);
        s1[jf] = mfma16(qf[1][kf], k1, s1[jf]);
      }
    }
    #pragma unroll
    for (int jf=0;jf<2;++jf)
      #pragma unroll
      for (int r=0;r<4;++r){
        int ij = (lg*4+r)*32 + jf*16 + lp;
        unsigned int pk = (unsigned int)f2bf(s0[jf][r]) | ((unsigned int)f2bf(s1[jf][r])<<16);
        *(unsigned int*)(smem + ij*80 + w*4) = pk;
      }
    __syncthreads();

    unsigned int mku0 = *(const unsigned int*)(mask + b*2048 + j0 + lg*4);
    unsigned int mku1 = *(const unsigned int*)(mask + b*2048 + j0 + 16 + lg*4);
    #pragma unroll
    for (int cc=0; cc<4; ++cc){
      int c = w*4+cc;
      bf16x8 afr = *(const bf16x8*)(smem + (c*16+lp)*80 + lg*16);
      f32x4 pa = mfma16(afr, preB, zero4());
      int il = 2*w + (cc>>1);
      int jl = (cc&1)*16 + lg*4;
      float4 pb = *(const float4*)&pos_bias[((size_t)lp*2048 + (i0+il))*2048 + j0 + jl];
      unsigned int mku = (cc&1) ? mku1 : mku0;
      float va0 = pa[0] + pb.x + bpre_g + (((mku    )&255u) ? -1e30f : 0.f);
      float va1 = pa[1] + pb.y + bpre_g + (((mku>> 8)&255u) ? -1e30f : 0.f);
      float va2 = pa[2] + pb.z + bpre_g + (((mku>>16)&255u) ? -1e30f : 0.f);
      float va3 = pa[3] + pb.w + bpre_g + (((mku>>24)&255u) ? -1e30f : 0.f);
      int ii = cc>>1;
      // normalized P -> same rows of S buffer, [ij][g] bf16
      int rowb = (c*16 + lg*4);
      *(unsigned short*)(smem + (rowb+0)*80 + lp*2) = f2bf(__expf(va0-mC[ii])*linvC[ii]);
      *(unsigned short*)(smem + (rowb+1)*80 + lp*2) = f2bf(__expf(va1-mC[ii])*linvC[ii]);
      *(unsigned short*)(smem + (rowb+2)*80 + lp*2) = f2bf(__expf(va2-mC[ii])*linvC[ii]);
      *(unsigned short*)(smem + (rowb+3)*80 + lp*2) = f2bf(__expf(va3-mC[ii])*linvC[ii]);
    }
    __syncthreads();

    // post-mix: Atilde[ij][g'] -> Al [g'*16+i][j] (packed 8B stores)
    #pragma unroll
    for (int cc=0; cc<4; ++cc){
      int c = w*4+cc;
      bf16x8 a2 = *(const bf16x8*)(smem + (c*16+lp)*80 + lg*16);
      f32x4 aa = mfma16(a2, postB, zero4());
      int il = 2*w + (cc>>1);
      int jl = (cc&1)*16 + lg*4;
      short4v av;
      av.x = (short)f2bf(aa[0]); av.y = (short)f2bf(aa[1]);
      av.z = (short)f2bf(aa[2]); av.w = (short)f2bf(aa[3]);
      *(short4v*)(smem + 40960 + (lp*16 + il)*80 + jl*2) = av;
    }
    __syncthreads();

    // PV
    #pragma unroll
    for (int hh=0; hh<2; ++hh){
      int gg = 2*w+hh;
      bf16x8 af = *(const bf16x8*)(smem + 40960 + (gg*16+lp)*80 + lg*16);
      #pragma unroll
      for (int df=0; df<4; ++df){
        bf16x8 vf = *(const bf16x8*)(vt + ((size_t)(b*16+gg)*64 + df*16 + lp)*2048 + j0 + lg*8);
        oacc[hh][df] = mfma16(af, vf, oacc[hh][df]);
      }
    }
  }

  float* po = js ? pout1 : pout0;
  #pragma unroll
  for (int hh=0; hh<2; ++hh){
    int gg = 2*w+hh;
    float bp = (js==0) ? bpost[gg] : 0.f;
    #pragma unroll
    for (int df=0; df<4; ++df){
      int d = df*16+lp;
      float vs = vsum[(b*16+gg)*64 + d];
      #pragma unroll
      for (int r=0;r<4;++r){
        po[((size_t)b*2048 + i0 + lg*4 + r)*1024 + gg*64 + d] = oacc[hh][df][r] + bp*vs;
      }
    }
  }
}

// ------------- combine partial outputs -> bf16 attn_out -------------
__global__ __launch_bounds__(256) void k_combine(const float* __restrict__ p0, const float* __restrict__ p1,
                                                 unsigned short* __restrict__ ao){
  int i = blockIdx.x*256 + threadIdx.x;
  float4 a = ((const float4*)p0)[i];
  float4 c = ((const float4*)p1)[i];
  short4v o;
  o.x=(short)f2bf(a.x+c.x); o.y=(short)f2bf(a.y+c.y);
  o.z=(short)f2bf(a.z+c.z); o.w=(short)f2bf(a.w+c.w);
  ((short4v*)ao)[i] = o;
}

// ======================================================================
extern "C" void kernel_launch(void* const* d_in, const int* in_sizes, int n_in,
                              void* d_out, int out_size, void* d_ws, size_t ws_size,
                              hipStream_t stream)
{
  const float* x        = (const float*)d_in[0];
  const float* pos_bias = (const float*)d_in[1];
  const unsigned char* mask = (const unsigned char*)d_in[2];
  const float* Wqkv     = (const float*)d_in[3];
  const float* Wout     = (const float*)d_in[4];
  const float* Wpre     = (const float*)d_in[5];
  const float* bpre     = (const float*)d_in[6];
  const float* Wpost    = (const float*)d_in[7];
  const float* bpost    = (const float*)d_in[8];
  const float* temp     = (const float*)d_in[9];
  float* out = (float*)d_out;
  float* kv_out = out + 4194304;

  char* ws = (char*)d_ws;
  // region map (reuse over time):
  unsigned short* XB    = (unsigned short*)(ws + 0);          // x bf16 (8.39MB) -> AO later
  unsigned short* WT    = (unsigned short*)(ws + 8388608);    // WqkvT bf16 (6.29MB) -> WOT/PART/smalls later
  unsigned short* WOT   = (unsigned short*)(ws + 8388608);    // 2.10MB
  float*          PART_M= (float*)        (ws + 10485760);    // 1.05MB
  float*          PART_L= (float*)        (ws + 11534336);    // 1.05MB
  unsigned short* WPRE  = (unsigned short*)(ws + 12582912);
  unsigned short* WPOST = (unsigned short*)(ws + 12583424);
  float*          VSUM  = (float*)        (ws + 12583936);
  unsigned short* QKV   = (unsigned short*)(ws + 14680064);   // 25.2MB -> VT + POUT0 later
  unsigned short* VT    = (unsigned short*)(ws + 14680064);   // 8.39MB
  float*          POUT0 = (float*)        (ws + 23068672);    // 16.78MB
  unsigned short* Q     = (unsigned short*)(ws + 39845888);   // 8.39MB
  unsigned short* KB    = (unsigned short*)(ws + 48234496);   // 8.39MB
  unsigned short* VB    = (unsigned short*)(ws + 56623104);   // 8.39MB (dead early)
  float*          POUT1 = (float*)        (ws + 56623104);    // 16.78MB (ends 73400320)
  unsigned short* AO    = XB;

  // 1. x -> bf16
  k_f32_to_bf16<<<4096, 256, 0, stream>>>(x, XB, 1048576);
  // 2. Wqkv [1024][3072] -> WT [3072][1024] bf16
  k_convT<<<dim3(96,32), 256, 0, stream>>>(Wqkv, WT, 1024, 3072);
  // 3. qkv = x @ Wqkv (bf16 out)
  k_gemm<0><<<dim3(24,32), 256, 0, stream>>>(XB, WT, (void*)QKV, 4096, 3072, 1024);
  // 4. split + l2norm + kv f32 output
  k_split_norm<<<16384, 256, 0, stream>>>(QKV, Q, KB, VB, kv_out);
  // 5. v -> vt
  k_transpose_v<<<dim3(32,32), 256, 0, stream>>>(VB, VT);
  // 6. vsum
  k_vsum<<<32, 256, 0, stream>>>(VB, VSUM);
  // 7. small weights prep
  k_prep<<<1, 256, 0, stream>>>(Wpre, Wpost, temp, WPRE, WPOST);
  // 8. Wout -> WOT (after gemm0 freed WT region)
  k_convT<<<dim3(32,32), 256, 0, stream>>>(Wout, WOT, 1024, 1024);
  // 9. pass 1 (j-split 4)
  k_pass1<<<1024, 512, 0, stream>>>(Q, KB, pos_bias, mask, WPRE, bpre, PART_M, PART_L);
  // 10. pass 2 (j-split 2)
  k_pass2<<<512, 512, 0, stream>>>(Q, KB, VT, pos_bias, mask, WPRE, WPOST, bpre, bpost, VSUM,
                                   PART_M, PART_L, POUT0, POUT1);
  // 11. combine partials -> AO bf16
  k_combine<<<4096, 256, 0, stream>>>(POUT0, POUT1, AO);
  // 12. out = attn_out @ Wout (f32 out)
  k_gemm<1><<<dim3(8,32), 256, 0, stream>>>(AO, WOT, d_out, 4096, 1024, 1024);
}